// Round 14
// baseline (172.602 us; speedup 1.0000x reference)
//
#include <hip/hip_runtime.h>
#include <hip/hip_bf16.h>
#include <math.h>

// IntegralTransform via bf16 MFMA (16x16x32), v12 "exact-residency grid":
//  - v11 post-mortem: launch-merge gave only ~2us; the ~68us graded-vs-steady
//    gap is harness-fixed. Steady kernel = 100us.
//  - NEW single-variable change: grid 1792 -> 1024. Residency is 4 blocks/CU
//    (VGPR 112); with grid 1792 all 1024 resident blocks finish their ~7
//    points SIMULTANEOUSLY (identical work), leaving a 768-block second
//    generation at 3/CU: total ~14 point-times. Grid 1024 = exact residency,
//    12.2 point-times + small ragged tail => ~12% predicted win. (v7's
//    1024->1792 change was confounded with the spill-fix; never isolated.)
//  - kernel body byte-identical to v11 (v9 codegen: transpose-free k-permuted
//    W2/W3, no-shfl loads, packed exp2 gelu, DPP reduce, merged prep).

typedef __attribute__((ext_vector_type(8))) short short8;
typedef __attribute__((ext_vector_type(4))) float floatx4;
typedef __attribute__((ext_vector_type(2))) float f32x2;
typedef __attribute__((ext_vector_type(4))) unsigned short ushort4v;

__device__ __forceinline__ unsigned short bf16rne(float f) {
    unsigned int u = __float_as_uint(f);
    u += 0x7fffu + ((u >> 16) & 1u);
    return (unsigned short)(u >> 16);
}
__device__ __forceinline__ unsigned int pk2(float a, float b) {
    union { __hip_bfloat162 h; unsigned int u; } cv;
    cv.h = __float22bfloat162_rn(make_float2(a, b));
    return cv.u;
}
__device__ __forceinline__ float bf16f(unsigned short u) {
    return __uint_as_float(((unsigned int)u) << 16);
}
// tanh-form gelu on a pair -> packed bf16x2.
// exp(2*0.7978845608*u) = 2^(x*(2.3022083 + 0.10294324*x^2)).
__device__ __forceinline__ unsigned int gelu2pk(f32x2 x) {
    f32x2 x2 = x * x;
    f32x2 t  = __builtin_elementwise_fma(x2, (f32x2)(0.10294324f),
                                         (f32x2)(2.3022083f));
    f32x2 a  = x * t;
    f32x2 e;
    e.x = __builtin_amdgcn_exp2f(a.x);
    e.y = __builtin_amdgcn_exp2f(a.y);
    f32x2 d = e + 1.0f;
    f32x2 r;
    r.x = __builtin_amdgcn_rcpf(d.x);
    r.y = __builtin_amdgcn_rcpf(d.y);
    f32x2 g = __builtin_elementwise_fma(-x, r, x);
    return pk2(g.x, g.y);
}

#define MFMA16(a, b, c) __builtin_amdgcn_mfma_f32_16x16x32_bf16(a, b, c, 0, 0, 0)

// DPP sum step within 16-lane row: 0x128=row_ror:8, 0x124=row_ror:4,
// 0x4E=quad_perm xor2, 0xB1=quad_perm xor1.
template<int CTRL>
__device__ __forceinline__ float dpp_add(float x) {
    int y = __builtin_amdgcn_update_dpp(0, __float_as_int(x), CTRL, 0xF, 0xF, true);
    return x + __int_as_float(y);
}
__device__ __forceinline__ float row16_sum(float x) {
    x = dpp_add<0x128>(x);
    x = dpp_add<0x124>(x);
    x = dpp_add<0x4E>(x);
    x = dpp_add<0xB1>(x);
    return x;
}

// ---- merged pre-pass: blocks 0..5 pack weights+biases; blocks >=6 cvt fy ----
// W1 (frags 0..7): B[k][n] identity-k with the agg permutation
//   (kp<32 -> fy row 6+kp; 32..37 -> y rows 0..5; 38 -> b1; else 0).
// W2 (frags 8..15), W3 (16..19): k-PERMUTED so layer-1/2 outputs feed the
//   next MFMA with no lane movement:
//   B[k=32kb+8q+j][n] = W[16*(m>>2) + 4q + (m&3)][n],  m = 8kb + j.
__global__ __launch_bounds__(256) void prep(
    const float* __restrict__ W1, const float* __restrict__ b1,
    const float* __restrict__ W2, const float* __restrict__ b2,
    const float* __restrict__ W3, const float* __restrict__ b3,
    unsigned short* __restrict__ wpack,
    const float* __restrict__ fy, unsigned short* __restrict__ fy16,
    int n8)
{
    if (blockIdx.x >= 6) {
        int i = (blockIdx.x - 6) * 256 + threadIdx.x;
        if (i >= n8) return;
        const float4* p = (const float4*)(fy + (size_t)i * 8);
        float4 a = p[0], b = p[1];
        *(uint4*)(fy16 + (size_t)i * 8) =
            make_uint4(pk2(a.x, a.y), pk2(a.z, a.w), pk2(b.x, b.y), pk2(b.z, b.w));
        return;
    }
    int t = blockIdx.x * 256 + threadIdx.x;
    if (t < 20 * 64) {
        int f = t >> 6, lane = t & 63;
        int quad = lane >> 4, c16 = lane & 15;
        unsigned short v8[8];
        if (f < 8) {
            int kb = f >> 2, nb = f & 3;
            #pragma unroll
            for (int j = 0; j < 8; ++j) {
                int kp = kb * 32 + quad * 8 + j;
                int n  = nb * 16 + c16;
                float v;
                if (kp < 32)      v = W1[(6 + kp) * 64 + n];
                else if (kp < 38) v = W1[(kp - 32) * 64 + n];
                else if (kp == 38) v = b1[n];
                else              v = 0.f;
                v8[j] = bf16rne(v);
            }
        } else if (f < 16) {
            int kb = (f - 8) >> 2, nb = (f - 8) & 3;
            #pragma unroll
            for (int j = 0; j < 8; ++j) {
                int m = 8 * kb + j;
                int row = 16 * (m >> 2) + 4 * quad + (m & 3);
                v8[j] = bf16rne(W2[row * 64 + nb * 16 + c16]);
            }
        } else {
            int kb = (f - 16) >> 1, nb = (f - 16) & 1;
            #pragma unroll
            for (int j = 0; j < 8; ++j) {
                int m = 8 * kb + j;
                int row = 16 * (m >> 2) + 4 * quad + (m & 3);
                v8[j] = bf16rne(W3[row * 32 + nb * 16 + c16]);
            }
        }
        uint4 o;
        o.x = (unsigned)v8[0] | ((unsigned)v8[1] << 16);
        o.y = (unsigned)v8[2] | ((unsigned)v8[3] << 16);
        o.z = (unsigned)v8[4] | ((unsigned)v8[5] << 16);
        o.w = (unsigned)v8[6] | ((unsigned)v8[7] << 16);
        *(uint4*)(wpack + (size_t)t * 8) = o;
    } else if (t < 1344) {               // b2tab: 64 floats
        int idx = t - 1280;
        float* btab = (float*)(wpack + 10240);
        btab[idx] = b2[16 * ((idx >> 2) & 3) + 4 * (idx >> 4) + (idx & 3)];
    } else if (t < 1376) {               // b3tab: 32 floats
        int idx = t - 1344;
        float* btab = (float*)(wpack + 10240);
        btab[64 + idx] = b3[16 * ((idx >> 2) & 1) + 4 * (idx >> 3) + (idx & 3)];
    }
}

__global__ __launch_bounds__(256, 4) void it_mfma(
    const float* __restrict__ y, const unsigned short* __restrict__ fy16,
    const float* __restrict__ wts,
    const unsigned short* __restrict__ wpack,
    const int* __restrict__ nbr,
    float* __restrict__ out, int npts)
{
    __shared__ unsigned short wlds[10432];   // 20864 B: frags + bias tables

    const int tid  = threadIdx.x;
    const int lane = tid & 63;
    const int wv   = tid >> 6;
    const int quad = lane >> 4;
    const int c16  = lane & 15;
    const int wgid   = blockIdx.x * 4 + wv;
    const int nwaves = gridDim.x * 4;

    // block-cooperative weight+bias load (before any early exit)
    {
        const uint4* src = (const uint4*)wpack;
        uint4* dst = (uint4*)wlds;
        #pragma unroll
        for (int i = 0; i < 6; ++i) {
            int idx = tid + i * 256;
            if (idx < 1304) dst[idx] = src[idx];
        }
    }
    __syncthreads();
    if (wgid >= npts) return;

    const floatx4 fz = {0.f, 0.f, 0.f, 0.f};
    const short8 s8z = {0,0,0,0,0,0,0,0};

    // ---- prologue: fetch first point's inputs (no shfl: direct loads) ----
    int p = wgid;
    int   j0c, j1c;
    float wac, wbc;
    short8 a0c[2], a1c[2];
    {
        const int pu0 = __builtin_amdgcn_readfirstlane(p);
        j0c = nbr[pu0 * 32 + c16];
        j1c = nbr[pu0 * 32 + 16 + c16];
        wac = wts[j0c]; wbc = wts[j1c];
        a0c[0] = *(const short8*)(fy16 + (size_t)j0c * 32 + quad * 8);
        a0c[1] = *(const short8*)(fy16 + (size_t)j1c * 32 + quad * 8);
        a1c[0] = s8z; a1c[1] = s8z;
        if (quad == 0) {
            float xa = y[3*pu0], xb = y[3*pu0+1], xc = y[3*pu0+2];
            float ja = y[3*j0c], jb = y[3*j0c+1], jc = y[3*j0c+2];
            float ka = y[3*j1c], kb = y[3*j1c+1], kc = y[3*j1c+2];
            union { short8 s; unsigned int u[4]; } c0, c1;
            c0.u[0] = pk2(ja, jb); c0.u[1] = pk2(jc, xa);
            c0.u[2] = pk2(xb, xc); c0.u[3] = pk2(1.0f, 0.0f);
            c1.u[0] = pk2(ka, kb); c1.u[1] = pk2(kc, xa);
            c1.u[2] = pk2(xb, xc); c1.u[3] = pk2(1.0f, 0.0f);
            a1c[0] = c0.s; a1c[1] = c1.s;
        }
    }

    unsigned woff = 0;   // asm barrier keeps LDS frag reads loop-variant
                         // (anti-LICM: hoisting 20 frags into regs = v2 spill)

    for (;;) {
        asm volatile("" : "+v"(woff));
        const unsigned short* wp = wlds + woff;
        const float* bp = (const float*)((const char*)wp + 20480);
        #define WFRAG(fid) (*(const short8*)(wp + (((fid) * 64 + lane) * 8)))

        const int pu = __builtin_amdgcn_readfirstlane(p);
        const int pn = p + nwaves;
        const bool last = (pn >= npts);
        const int pncu = __builtin_amdgcn_readfirstlane(last ? p : pn);
        // issue next-point's nbr loads early (L1/L2-hot 64B broadcasts)
        int j0n = nbr[pncu * 32 + c16];
        int j1n = nbr[pncu * 32 + 16 + c16];

        // ---- layer 1, both tiles (each W1 frag read once) ----
        floatx4 acc0[4], acc1[4];
        #pragma unroll
        for (int mb = 0; mb < 4; ++mb) {
            short8 w = WFRAG(mb);
            acc0[mb] = MFMA16(w, a0c[0], fz);
            acc1[mb] = MFMA16(w, a0c[1], fz);
        }
        #pragma unroll
        for (int mb = 0; mb < 4; ++mb) {
            short8 w = WFRAG(4 + mb);
            acc0[mb] = MFMA16(w, a1c[0], acc0[mb]);
            acc1[mb] = MFMA16(w, a1c[1], acc1[mb]);
        }
        // gelu (b1 folded into MFMA) + pack; no transpose (k-permuted W2)
        unsigned u0[8], u1[8];
        #pragma unroll
        for (int mb = 0; mb < 4; ++mb) {
            u0[mb*2]   = gelu2pk((f32x2){acc0[mb][0], acc0[mb][1]});
            u0[mb*2+1] = gelu2pk((f32x2){acc0[mb][2], acc0[mb][3]});
            u1[mb*2]   = gelu2pk((f32x2){acc1[mb][0], acc1[mb][1]});
            u1[mb*2+1] = gelu2pk((f32x2){acc1[mb][2], acc1[mb][3]});
        }
        short8 hb00, hb10, hb01, hb11;
        {
            union { unsigned u[4]; short8 s; } c;
            c.u[0]=u0[0]; c.u[1]=u0[1]; c.u[2]=u0[2]; c.u[3]=u0[3]; hb00 = c.s;
            c.u[0]=u0[4]; c.u[1]=u0[5]; c.u[2]=u0[6]; c.u[3]=u0[7]; hb10 = c.s;
            c.u[0]=u1[0]; c.u[1]=u1[1]; c.u[2]=u1[2]; c.u[3]=u1[3]; hb01 = c.s;
            c.u[0]=u1[4]; c.u[1]=u1[5]; c.u[2]=u1[6]; c.u[3]=u1[7]; hb11 = c.s;
        }

        // ---- prefetch next point (hidden under layers 2/3; no shfl) ----
        short8 a0n[2], a1n[2];
        float wan, wbn;
        {
            a0n[0] = *(const short8*)(fy16 + (size_t)j0n * 32 + quad * 8);
            a0n[1] = *(const short8*)(fy16 + (size_t)j1n * 32 + quad * 8);
            wan = wts[j0n]; wbn = wts[j1n];
            a1n[0] = s8z; a1n[1] = s8z;
            if (quad == 0) {
                float xa = y[3*pncu], xb = y[3*pncu+1], xc = y[3*pncu+2];
                float ja = y[3*j0n], jb = y[3*j0n+1], jc = y[3*j0n+2];
                float ka = y[3*j1n], kb = y[3*j1n+1], kc = y[3*j1n+2];
                union { short8 s; unsigned int u[4]; } c0, c1;
                c0.u[0] = pk2(ja, jb); c0.u[1] = pk2(jc, xa);
                c0.u[2] = pk2(xb, xc); c0.u[3] = pk2(1.0f, 0.0f);
                c1.u[0] = pk2(ka, kb); c1.u[1] = pk2(kc, xa);
                c1.u[2] = pk2(xb, xc); c1.u[3] = pk2(1.0f, 0.0f);
                a1n[0] = c0.s; a1n[1] = c1.s;
            }
        }

        // ---- layer 2, both tiles (k-permuted W2 frags) ----
        #pragma unroll
        for (int mb = 0; mb < 4; ++mb) {
            short8 w = WFRAG(8 + mb);
            acc0[mb] = MFMA16(w, hb00, fz);
            acc1[mb] = MFMA16(w, hb01, fz);
        }
        #pragma unroll
        for (int mb = 0; mb < 4; ++mb) {
            short8 w = WFRAG(12 + mb);
            acc0[mb] = MFMA16(w, hb10, acc0[mb]);
            acc1[mb] = MFMA16(w, hb11, acc1[mb]);
        }
        #pragma unroll
        for (int mb = 0; mb < 4; ++mb) {
            floatx4 b2v = *(const floatx4*)(bp + quad * 16 + mb * 4);
            u0[mb*2]   = gelu2pk((f32x2){acc0[mb][0] + b2v[0], acc0[mb][1] + b2v[1]});
            u0[mb*2+1] = gelu2pk((f32x2){acc0[mb][2] + b2v[2], acc0[mb][3] + b2v[3]});
            u1[mb*2]   = gelu2pk((f32x2){acc1[mb][0] + b2v[0], acc1[mb][1] + b2v[1]});
            u1[mb*2+1] = gelu2pk((f32x2){acc1[mb][2] + b2v[2], acc1[mb][3] + b2v[3]});
        }
        short8 gb00, gb10, gb01, gb11;
        {
            union { unsigned u[4]; short8 s; } c;
            c.u[0]=u0[0]; c.u[1]=u0[1]; c.u[2]=u0[2]; c.u[3]=u0[3]; gb00 = c.s;
            c.u[0]=u0[4]; c.u[1]=u0[5]; c.u[2]=u0[6]; c.u[3]=u0[7]; gb10 = c.s;
            c.u[0]=u1[0]; c.u[1]=u1[1]; c.u[2]=u1[2]; c.u[3]=u1[3]; gb01 = c.s;
            c.u[0]=u1[4]; c.u[1]=u1[5]; c.u[2]=u1[6]; c.u[3]=u1[7]; gb11 = c.s;
        }

        // ---- layer 3, both tiles (k-permuted W3 frags, each read once) ----
        floatx4 o00, o10, o01, o11;
        { short8 w = WFRAG(16); o00 = MFMA16(w, gb00, fz); o01 = MFMA16(w, gb01, fz); }
        { short8 w = WFRAG(18); o00 = MFMA16(w, gb10, o00); o01 = MFMA16(w, gb11, o01); }
        { short8 w = WFRAG(17); o10 = MFMA16(w, gb00, fz); o11 = MFMA16(w, gb01, fz); }
        { short8 w = WFRAG(19); o10 = MFMA16(w, gb10, o10); o11 = MFMA16(w, gb11, o11); }

        floatx4 b3v0 = *(const floatx4*)(bp + 64 + quad * 8);
        floatx4 b3v1 = *(const floatx4*)(bp + 64 + quad * 8 + 4);

        // ---- epilogue: ch = 16mb + 4quad + r; edge c16 (t0) / 16+c16 (t1) ----
        float vs0[4] = {0.f, 0.f, 0.f, 0.f};
        float vs1[4] = {0.f, 0.f, 0.f, 0.f};
        {
            ushort4v fa = *(const ushort4v*)(fy16 + (size_t)j0c * 32 + 4 * quad);
            ushort4v fb = *(const ushort4v*)(fy16 + (size_t)j0c * 32 + 16 + 4 * quad);
            #pragma unroll
            for (int r = 0; r < 4; ++r) {
                vs0[r] = fmaf((o00[r] + b3v0[r]) * bf16f(fa[r]), wac, vs0[r]);
                vs1[r] = fmaf((o10[r] + b3v1[r]) * bf16f(fb[r]), wac, vs1[r]);
            }
        }
        {
            ushort4v fa = *(const ushort4v*)(fy16 + (size_t)j1c * 32 + 4 * quad);
            ushort4v fb = *(const ushort4v*)(fy16 + (size_t)j1c * 32 + 16 + 4 * quad);
            #pragma unroll
            for (int r = 0; r < 4; ++r) {
                vs0[r] = fmaf((o01[r] + b3v0[r]) * bf16f(fa[r]), wbc, vs0[r]);
                vs1[r] = fmaf((o11[r] + b3v1[r]) * bf16f(fb[r]), wbc, vs1[r]);
            }
        }
        #undef WFRAG

        // ---- reduce over the 16 edge-lanes via DPP (no DS ops) and store ----
        #pragma unroll
        for (int r = 0; r < 4; ++r) {
            vs0[r] = row16_sum(vs0[r]);
            vs1[r] = row16_sum(vs1[r]);
        }
        if (c16 == 0) {
            *(float4*)(out + (size_t)pu * 32 + 4 * quad) =
                make_float4(vs0[0], vs0[1], vs0[2], vs0[3]);
            *(float4*)(out + (size_t)pu * 32 + 16 + 4 * quad) =
                make_float4(vs1[0], vs1[1], vs1[2], vs1[3]);
        }

        if (last) break;
        p = pn;
        j0c = j0n; j1c = j1n; wac = wan; wbc = wbn;
        a0c[0] = a0n[0]; a0c[1] = a0n[1];
        a1c[0] = a1n[0]; a1c[1] = a1n[1];
    }
}

extern "C" void kernel_launch(void* const* d_in, const int* in_sizes, int n_in,
                              void* d_out, int out_size, void* d_ws, size_t ws_size,
                              hipStream_t stream) {
    const float* y  = (const float*)d_in[0];
    const float* fy = (const float*)d_in[1];
    const float* wt = (const float*)d_in[2];
    const float* W1 = (const float*)d_in[3];
    const float* b1 = (const float*)d_in[4];
    const float* W2 = (const float*)d_in[5];
    const float* b2 = (const float*)d_in[6];
    const float* W3 = (const float*)d_in[7];
    const float* b3 = (const float*)d_in[8];
    const int* nbr  = (const int*)d_in[9];
    const int E = in_sizes[9];
    const int npts = E >> 5;              // K = 32 fixed
    float* out = (float*)d_out;

    // workspace: [0, 20864) packed frags + bias tables; [32768, ...) fy16
    unsigned short* wpack = (unsigned short*)d_ws;
    unsigned short* fy16  = (unsigned short*)((char*)d_ws + 32768);

    // single merged pre-pass (one launch)
    const int n8 = npts * 4;              // 8 floats per thread
    hipLaunchKernelGGL(prep, dim3(6 + (n8 + 255) / 256), dim3(256), 0, stream,
                       W1, b1, W2, b2, W3, b3, wpack, fy, fy16, n8);

    // grid = EXACT residency: 4 blocks/CU x 256 CU = 1024. Grid 1792 ran a
    // 768-block second generation at 3/CU (all blocks finish simultaneously)
    // => ~14 point-times vs 12.2 at grid 1024.
    hipLaunchKernelGGL(it_mfma, dim3(1024), dim3(256), 0, stream,
                       y, fy16, wt, wpack, nbr, out, npts);
}

// Round 15
// 170.150 us; speedup vs baseline: 1.0144x; 1.0144x over previous
//
#include <hip/hip_runtime.h>
#include <hip/hip_bf16.h>
#include <math.h>

// IntegralTransform via bf16 MFMA (16x16x32), v13 "register diet -> clean 5 waves":
//  - v12 post-mortem: grid 1024 (104us) < grid 1792 (100us): generation-
//    quantization model refuted; 1792 fills stragglers. Grid reverted.
//  - v10 retro: (256,5) spilled only ~9 regs (demand ~105 vs cap 96). v13
//    removes ~10 regs of loop-carried state STRUCTURALLY:
//      * a1n[2] prefetch (16 regs, mostly zeros) -> 6 packed u32 (pk2 pairs);
//        a1 operand assembled at use (few cndmask ops; bias word = literal).
//      * wac/wbc/wan/wbn dropped; wts re-loaded before layer 3 (v10-verified).
//    Demand ~95 <= 96 -> clean 5 waves/SIMD (+25% TLP, latency-bound kernel).
//  - pre-committed checks: WRITE_SIZE > 8MB => spill => revert to v11;
//    flat dur at clean 96 => occupancy axis closed for good.
//  - keeps: transpose-free k-permuted W2/W3, no-shfl loads, packed exp2 gelu,
//    DPP reduce, layer-major single-read weight frags, merged prep, grid 1792.

typedef __attribute__((ext_vector_type(8))) short short8;
typedef __attribute__((ext_vector_type(4))) float floatx4;
typedef __attribute__((ext_vector_type(2))) float f32x2;
typedef __attribute__((ext_vector_type(4))) unsigned short ushort4v;

__device__ __forceinline__ unsigned short bf16rne(float f) {
    unsigned int u = __float_as_uint(f);
    u += 0x7fffu + ((u >> 16) & 1u);
    return (unsigned short)(u >> 16);
}
__device__ __forceinline__ unsigned int pk2(float a, float b) {
    union { __hip_bfloat162 h; unsigned int u; } cv;
    cv.h = __float22bfloat162_rn(make_float2(a, b));
    return cv.u;
}
__device__ __forceinline__ float bf16f(unsigned short u) {
    return __uint_as_float(((unsigned int)u) << 16);
}
// tanh-form gelu on a pair -> packed bf16x2.
// exp(2*0.7978845608*u) = 2^(x*(2.3022083 + 0.10294324*x^2)).
__device__ __forceinline__ unsigned int gelu2pk(f32x2 x) {
    f32x2 x2 = x * x;
    f32x2 t  = __builtin_elementwise_fma(x2, (f32x2)(0.10294324f),
                                         (f32x2)(2.3022083f));
    f32x2 a  = x * t;
    f32x2 e;
    e.x = __builtin_amdgcn_exp2f(a.x);
    e.y = __builtin_amdgcn_exp2f(a.y);
    f32x2 d = e + 1.0f;
    f32x2 r;
    r.x = __builtin_amdgcn_rcpf(d.x);
    r.y = __builtin_amdgcn_rcpf(d.y);
    f32x2 g = __builtin_elementwise_fma(-x, r, x);
    return pk2(g.x, g.y);
}

#define MFMA16(a, b, c) __builtin_amdgcn_mfma_f32_16x16x32_bf16(a, b, c, 0, 0, 0)

// DPP sum step within 16-lane row: 0x128=row_ror:8, 0x124=row_ror:4,
// 0x4E=quad_perm xor2, 0xB1=quad_perm xor1.
template<int CTRL>
__device__ __forceinline__ float dpp_add(float x) {
    int y = __builtin_amdgcn_update_dpp(0, __float_as_int(x), CTRL, 0xF, 0xF, true);
    return x + __int_as_float(y);
}
__device__ __forceinline__ float row16_sum(float x) {
    x = dpp_add<0x128>(x);
    x = dpp_add<0x124>(x);
    x = dpp_add<0x4E>(x);
    x = dpp_add<0xB1>(x);
    return x;
}

// ---- merged pre-pass: blocks 0..5 pack weights+biases; blocks >=6 cvt fy ----
// W1 (frags 0..7): B[k][n] identity-k with the agg permutation
//   (kp<32 -> fy row 6+kp; 32..37 -> y rows 0..5; 38 -> b1; else 0).
// W2 (frags 8..15), W3 (16..19): k-PERMUTED so layer-1/2 outputs feed the
//   next MFMA with no lane movement:
//   B[k=32kb+8q+j][n] = W[16*(m>>2) + 4q + (m&3)][n],  m = 8kb + j.
__global__ __launch_bounds__(256) void prep(
    const float* __restrict__ W1, const float* __restrict__ b1,
    const float* __restrict__ W2, const float* __restrict__ b2,
    const float* __restrict__ W3, const float* __restrict__ b3,
    unsigned short* __restrict__ wpack,
    const float* __restrict__ fy, unsigned short* __restrict__ fy16,
    int n8)
{
    if (blockIdx.x >= 6) {
        int i = (blockIdx.x - 6) * 256 + threadIdx.x;
        if (i >= n8) return;
        const float4* p = (const float4*)(fy + (size_t)i * 8);
        float4 a = p[0], b = p[1];
        *(uint4*)(fy16 + (size_t)i * 8) =
            make_uint4(pk2(a.x, a.y), pk2(a.z, a.w), pk2(b.x, b.y), pk2(b.z, b.w));
        return;
    }
    int t = blockIdx.x * 256 + threadIdx.x;
    if (t < 20 * 64) {
        int f = t >> 6, lane = t & 63;
        int quad = lane >> 4, c16 = lane & 15;
        unsigned short v8[8];
        if (f < 8) {
            int kb = f >> 2, nb = f & 3;
            #pragma unroll
            for (int j = 0; j < 8; ++j) {
                int kp = kb * 32 + quad * 8 + j;
                int n  = nb * 16 + c16;
                float v;
                if (kp < 32)      v = W1[(6 + kp) * 64 + n];
                else if (kp < 38) v = W1[(kp - 32) * 64 + n];
                else if (kp == 38) v = b1[n];
                else              v = 0.f;
                v8[j] = bf16rne(v);
            }
        } else if (f < 16) {
            int kb = (f - 8) >> 2, nb = (f - 8) & 3;
            #pragma unroll
            for (int j = 0; j < 8; ++j) {
                int m = 8 * kb + j;
                int row = 16 * (m >> 2) + 4 * quad + (m & 3);
                v8[j] = bf16rne(W2[row * 64 + nb * 16 + c16]);
            }
        } else {
            int kb = (f - 16) >> 1, nb = (f - 16) & 1;
            #pragma unroll
            for (int j = 0; j < 8; ++j) {
                int m = 8 * kb + j;
                int row = 16 * (m >> 2) + 4 * quad + (m & 3);
                v8[j] = bf16rne(W3[row * 32 + nb * 16 + c16]);
            }
        }
        uint4 o;
        o.x = (unsigned)v8[0] | ((unsigned)v8[1] << 16);
        o.y = (unsigned)v8[2] | ((unsigned)v8[3] << 16);
        o.z = (unsigned)v8[4] | ((unsigned)v8[5] << 16);
        o.w = (unsigned)v8[6] | ((unsigned)v8[7] << 16);
        *(uint4*)(wpack + (size_t)t * 8) = o;
    } else if (t < 1344) {               // b2tab: 64 floats
        int idx = t - 1280;
        float* btab = (float*)(wpack + 10240);
        btab[idx] = b2[16 * ((idx >> 2) & 3) + 4 * (idx >> 4) + (idx & 3)];
    } else if (t < 1376) {               // b3tab: 32 floats
        int idx = t - 1344;
        float* btab = (float*)(wpack + 10240);
        btab[64 + idx] = b3[16 * ((idx >> 2) & 1) + 4 * (idx >> 3) + (idx & 3)];
    }
}

__global__ __launch_bounds__(256, 5) void it_mfma(
    const float* __restrict__ y, const unsigned short* __restrict__ fy16,
    const float* __restrict__ wts,
    const unsigned short* __restrict__ wpack,
    const int* __restrict__ nbr,
    float* __restrict__ out, int npts)
{
    __shared__ unsigned short wlds[10432];   // 20864 B: frags + bias tables

    const int tid  = threadIdx.x;
    const int lane = tid & 63;
    const int wv   = tid >> 6;
    const int quad = lane >> 4;
    const int c16  = lane & 15;
    const int wgid   = blockIdx.x * 4 + wv;
    const int nwaves = gridDim.x * 4;

    // block-cooperative weight+bias load (before any early exit)
    {
        const uint4* src = (const uint4*)wpack;
        uint4* dst = (uint4*)wlds;
        #pragma unroll
        for (int i = 0; i < 6; ++i) {
            int idx = tid + i * 256;
            if (idx < 1304) dst[idx] = src[idx];
        }
    }
    __syncthreads();
    if (wgid >= npts) return;

    const floatx4 fz = {0.f, 0.f, 0.f, 0.f};
    const short8 s8z = {0,0,0,0,0,0,0,0};

    // ---- prologue: fetch first point's inputs (no shfl: direct loads) ----
    // a1 state kept as 3 packed u32 per tile (y0c/y1c), NOT short8 (reg diet).
    int p = wgid;
    int   j0c, j1c;
    short8 a0c[2];
    unsigned y0c[3] = {0u, 0u, 0u}, y1c[3] = {0u, 0u, 0u};
    {
        const int pu0 = __builtin_amdgcn_readfirstlane(p);
        j0c = nbr[pu0 * 32 + c16];
        j1c = nbr[pu0 * 32 + 16 + c16];
        a0c[0] = *(const short8*)(fy16 + (size_t)j0c * 32 + quad * 8);
        a0c[1] = *(const short8*)(fy16 + (size_t)j1c * 32 + quad * 8);
        if (quad == 0) {
            float xa = y[3*pu0], xb = y[3*pu0+1], xc = y[3*pu0+2];
            float ja = y[3*j0c], jb = y[3*j0c+1], jc = y[3*j0c+2];
            float ka = y[3*j1c], kb = y[3*j1c+1], kc = y[3*j1c+2];
            y0c[0] = pk2(ja, jb); y0c[1] = pk2(jc, xa); y0c[2] = pk2(xb, xc);
            y1c[0] = pk2(ka, kb); y1c[1] = pk2(kc, xa); y1c[2] = pk2(xb, xc);
        }
    }

    unsigned woff = 0;   // asm barrier keeps LDS frag reads loop-variant
                         // (anti-LICM: hoisting 20 frags into regs = v2 spill)

    for (;;) {
        asm volatile("" : "+v"(woff));
        const unsigned short* wp = wlds + woff;
        const float* bp = (const float*)((const char*)wp + 20480);
        #define WFRAG(fid) (*(const short8*)(wp + (((fid) * 64 + lane) * 8)))

        const int pu = __builtin_amdgcn_readfirstlane(p);
        const int pn = p + nwaves;
        const bool last = (pn >= npts);
        const int pncu = __builtin_amdgcn_readfirstlane(last ? p : pn);
        // issue next-point's nbr loads early (L1/L2-hot 64B broadcasts)
        int j0n = nbr[pncu * 32 + c16];
        int j1n = nbr[pncu * 32 + 16 + c16];

        // ---- assemble a1 operands from packed y state (quad0 only; k=38
        //      bias word = bf16(1.0) literal 0x00003f80) ----
        short8 a1t0 = s8z, a1t1 = s8z;
        if (quad == 0) {
            union { short8 s; unsigned int u[4]; } c0, c1;
            c0.u[0] = y0c[0]; c0.u[1] = y0c[1]; c0.u[2] = y0c[2]; c0.u[3] = 0x00003f80u;
            c1.u[0] = y1c[0]; c1.u[1] = y1c[1]; c1.u[2] = y1c[2]; c1.u[3] = 0x00003f80u;
            a1t0 = c0.s; a1t1 = c1.s;
        }

        // ---- layer 1, both tiles (each W1 frag read once) ----
        floatx4 acc0[4], acc1[4];
        #pragma unroll
        for (int mb = 0; mb < 4; ++mb) {
            short8 w = WFRAG(mb);
            acc0[mb] = MFMA16(w, a0c[0], fz);
            acc1[mb] = MFMA16(w, a0c[1], fz);
        }
        #pragma unroll
        for (int mb = 0; mb < 4; ++mb) {
            short8 w = WFRAG(4 + mb);
            acc0[mb] = MFMA16(w, a1t0, acc0[mb]);
            acc1[mb] = MFMA16(w, a1t1, acc1[mb]);
        }
        // gelu (b1 folded into MFMA) + pack; no transpose (k-permuted W2)
        unsigned u0[8], u1[8];
        #pragma unroll
        for (int mb = 0; mb < 4; ++mb) {
            u0[mb*2]   = gelu2pk((f32x2){acc0[mb][0], acc0[mb][1]});
            u0[mb*2+1] = gelu2pk((f32x2){acc0[mb][2], acc0[mb][3]});
            u1[mb*2]   = gelu2pk((f32x2){acc1[mb][0], acc1[mb][1]});
            u1[mb*2+1] = gelu2pk((f32x2){acc1[mb][2], acc1[mb][3]});
        }
        short8 hb00, hb10, hb01, hb11;
        {
            union { unsigned u[4]; short8 s; } c;
            c.u[0]=u0[0]; c.u[1]=u0[1]; c.u[2]=u0[2]; c.u[3]=u0[3]; hb00 = c.s;
            c.u[0]=u0[4]; c.u[1]=u0[5]; c.u[2]=u0[6]; c.u[3]=u0[7]; hb10 = c.s;
            c.u[0]=u1[0]; c.u[1]=u1[1]; c.u[2]=u1[2]; c.u[3]=u1[3]; hb01 = c.s;
            c.u[0]=u1[4]; c.u[1]=u1[5]; c.u[2]=u1[6]; c.u[3]=u1[7]; hb11 = c.s;
        }

        // ---- prefetch next point (hidden under layers 2/3; no shfl) ----
        short8 a0n[2];
        unsigned y0n[3] = {0u, 0u, 0u}, y1n[3] = {0u, 0u, 0u};
        {
            a0n[0] = *(const short8*)(fy16 + (size_t)j0n * 32 + quad * 8);
            a0n[1] = *(const short8*)(fy16 + (size_t)j1n * 32 + quad * 8);
            if (quad == 0) {
                float xa = y[3*pncu], xb = y[3*pncu+1], xc = y[3*pncu+2];
                float ja = y[3*j0n], jb = y[3*j0n+1], jc = y[3*j0n+2];
                float ka = y[3*j1n], kb = y[3*j1n+1], kc = y[3*j1n+2];
                y0n[0] = pk2(ja, jb); y0n[1] = pk2(jc, xa); y0n[2] = pk2(xb, xc);
                y1n[0] = pk2(ka, kb); y1n[1] = pk2(kc, xa); y1n[2] = pk2(xb, xc);
            }
        }

        // ---- layer 2, both tiles (k-permuted W2 frags) ----
        #pragma unroll
        for (int mb = 0; mb < 4; ++mb) {
            short8 w = WFRAG(8 + mb);
            acc0[mb] = MFMA16(w, hb00, fz);
            acc1[mb] = MFMA16(w, hb01, fz);
        }
        #pragma unroll
        for (int mb = 0; mb < 4; ++mb) {
            short8 w = WFRAG(12 + mb);
            acc0[mb] = MFMA16(w, hb10, acc0[mb]);
            acc1[mb] = MFMA16(w, hb11, acc1[mb]);
        }
        #pragma unroll
        for (int mb = 0; mb < 4; ++mb) {
            floatx4 b2v = *(const floatx4*)(bp + quad * 16 + mb * 4);
            u0[mb*2]   = gelu2pk((f32x2){acc0[mb][0] + b2v[0], acc0[mb][1] + b2v[1]});
            u0[mb*2+1] = gelu2pk((f32x2){acc0[mb][2] + b2v[2], acc0[mb][3] + b2v[3]});
            u1[mb*2]   = gelu2pk((f32x2){acc1[mb][0] + b2v[0], acc1[mb][1] + b2v[1]});
            u1[mb*2+1] = gelu2pk((f32x2){acc1[mb][2] + b2v[2], acc1[mb][3] + b2v[3]});
        }
        short8 gb00, gb10, gb01, gb11;
        {
            union { unsigned u[4]; short8 s; } c;
            c.u[0]=u0[0]; c.u[1]=u0[1]; c.u[2]=u0[2]; c.u[3]=u0[3]; gb00 = c.s;
            c.u[0]=u0[4]; c.u[1]=u0[5]; c.u[2]=u0[6]; c.u[3]=u0[7]; gb10 = c.s;
            c.u[0]=u1[0]; c.u[1]=u1[1]; c.u[2]=u1[2]; c.u[3]=u1[3]; gb01 = c.s;
            c.u[0]=u1[4]; c.u[1]=u1[5]; c.u[2]=u1[6]; c.u[3]=u1[7]; gb11 = c.s;
        }

        // wts loads (L1-hot broadcast); latency hides under W3 MFMAs
        float wac = wts[j0c], wbc = wts[j1c];

        // ---- layer 3, both tiles (k-permuted W3 frags, each read once) ----
        floatx4 o00, o10, o01, o11;
        { short8 w = WFRAG(16); o00 = MFMA16(w, gb00, fz); o01 = MFMA16(w, gb01, fz); }
        { short8 w = WFRAG(18); o00 = MFMA16(w, gb10, o00); o01 = MFMA16(w, gb11, o01); }
        { short8 w = WFRAG(17); o10 = MFMA16(w, gb00, fz); o11 = MFMA16(w, gb01, fz); }
        { short8 w = WFRAG(19); o10 = MFMA16(w, gb10, o10); o11 = MFMA16(w, gb11, o11); }

        floatx4 b3v0 = *(const floatx4*)(bp + 64 + quad * 8);
        floatx4 b3v1 = *(const floatx4*)(bp + 64 + quad * 8 + 4);

        // ---- epilogue: ch = 16mb + 4quad + r; edge c16 (t0) / 16+c16 (t1) ----
        float vs0[4] = {0.f, 0.f, 0.f, 0.f};
        float vs1[4] = {0.f, 0.f, 0.f, 0.f};
        {
            ushort4v fa = *(const ushort4v*)(fy16 + (size_t)j0c * 32 + 4 * quad);
            ushort4v fb = *(const ushort4v*)(fy16 + (size_t)j0c * 32 + 16 + 4 * quad);
            #pragma unroll
            for (int r = 0; r < 4; ++r) {
                vs0[r] = fmaf((o00[r] + b3v0[r]) * bf16f(fa[r]), wac, vs0[r]);
                vs1[r] = fmaf((o10[r] + b3v1[r]) * bf16f(fb[r]), wac, vs1[r]);
            }
        }
        {
            ushort4v fa = *(const ushort4v*)(fy16 + (size_t)j1c * 32 + 4 * quad);
            ushort4v fb = *(const ushort4v*)(fy16 + (size_t)j1c * 32 + 16 + 4 * quad);
            #pragma unroll
            for (int r = 0; r < 4; ++r) {
                vs0[r] = fmaf((o01[r] + b3v0[r]) * bf16f(fa[r]), wbc, vs0[r]);
                vs1[r] = fmaf((o11[r] + b3v1[r]) * bf16f(fb[r]), wbc, vs1[r]);
            }
        }
        #undef WFRAG

        // ---- reduce over the 16 edge-lanes via DPP (no DS ops) and store ----
        #pragma unroll
        for (int r = 0; r < 4; ++r) {
            vs0[r] = row16_sum(vs0[r]);
            vs1[r] = row16_sum(vs1[r]);
        }
        if (c16 == 0) {
            *(float4*)(out + (size_t)pu * 32 + 4 * quad) =
                make_float4(vs0[0], vs0[1], vs0[2], vs0[3]);
            *(float4*)(out + (size_t)pu * 32 + 16 + 4 * quad) =
                make_float4(vs1[0], vs1[1], vs1[2], vs1[3]);
        }

        if (last) break;
        p = pn;
        j0c = j0n; j1c = j1n;
        a0c[0] = a0n[0]; a0c[1] = a0n[1];
        y0c[0] = y0n[0]; y0c[1] = y0n[1]; y0c[2] = y0n[2];
        y1c[0] = y1n[0]; y1c[1] = y1n[1]; y1c[2] = y1n[2];
    }
}

extern "C" void kernel_launch(void* const* d_in, const int* in_sizes, int n_in,
                              void* d_out, int out_size, void* d_ws, size_t ws_size,
                              hipStream_t stream) {
    const float* y  = (const float*)d_in[0];
    const float* fy = (const float*)d_in[1];
    const float* wt = (const float*)d_in[2];
    const float* W1 = (const float*)d_in[3];
    const float* b1 = (const float*)d_in[4];
    const float* W2 = (const float*)d_in[5];
    const float* b2 = (const float*)d_in[6];
    const float* W3 = (const float*)d_in[7];
    const float* b3 = (const float*)d_in[8];
    const int* nbr  = (const int*)d_in[9];
    const int E = in_sizes[9];
    const int npts = E >> 5;              // K = 32 fixed
    float* out = (float*)d_out;

    // workspace: [0, 20864) packed frags + bias tables; [32768, ...) fy16
    unsigned short* wpack = (unsigned short*)d_ws;
    unsigned short* fy16  = (unsigned short*)((char*)d_ws + 32768);

    // single merged pre-pass (one launch)
    const int n8 = npts * 4;              // 8 floats per thread
    hipLaunchKernelGGL(prep, dim3(6 + (n8 + 255) / 256), dim3(256), 0, stream,
                       W1, b1, W2, b2, W3, b3, wpack, fy, fy16, n8);

    // grid 1792 (beats exact-residency 1024: fills stragglers). Target:
    // clean 5 blocks/CU via (256,5) cap with ~95-reg demand (no spill).
    hipLaunchKernelGGL(it_mfma, dim3(1792), dim3(256), 0, stream,
                       y, fy16, wt, wpack, nbr, out, npts);
}

// Round 16
// 167.019 us; speedup vs baseline: 1.0334x; 1.0187x over previous
//
#include <hip/hip_runtime.h>
#include <hip/hip_bf16.h>
#include <math.h>

// IntegralTransform via bf16 MFMA (16x16x32), v14 "tile-split pipeline":
//  - v13 post-mortem: (256,5) cap spilled again (WRITE 17MB) -> occupancy
//    axis CLOSED (3 data points). Revert to (256,4), 4 waves/SIMD.
//  - Issue accounting: ~1225 SIMD-cyc/point/wave available, stream ~1250
//    (620 VALU + ~512 trans + mem/MFMA issue) -> issue-bound, but VALUBusy
//    65% = layer-boundary stalls (strict MFMA->gelu->MFMA chain/point).
//  - v14 claims idle slots INTRA-wave: tile-split software pipeline. gelu of
//    tile1 runs while tile0's L2 MFMAs are in the matrix pipe, etc.:
//    L1(both) -> g(t0) -> L2(t0) || prefetch+g(t1) -> L2(t1) || g2(t0) ->
//    L3(t0) || g2(t1) -> L3(t1) -> epilogue. Pure reorder, bit-identical
//    numerics; +4 ds_read/point (W3 frags re-read per tile).
//  - keeps: transpose-free k-permuted W2/W3, no-shfl loads, packed exp2 gelu,
//    DPP reduce, packed-y a1 state (reg diet), merged prep, grid 1792.

typedef __attribute__((ext_vector_type(8))) short short8;
typedef __attribute__((ext_vector_type(4))) float floatx4;
typedef __attribute__((ext_vector_type(2))) float f32x2;
typedef __attribute__((ext_vector_type(4))) unsigned short ushort4v;

__device__ __forceinline__ unsigned short bf16rne(float f) {
    unsigned int u = __float_as_uint(f);
    u += 0x7fffu + ((u >> 16) & 1u);
    return (unsigned short)(u >> 16);
}
__device__ __forceinline__ unsigned int pk2(float a, float b) {
    union { __hip_bfloat162 h; unsigned int u; } cv;
    cv.h = __float22bfloat162_rn(make_float2(a, b));
    return cv.u;
}
__device__ __forceinline__ float bf16f(unsigned short u) {
    return __uint_as_float(((unsigned int)u) << 16);
}
// tanh-form gelu on a pair -> packed bf16x2.
// exp(2*0.7978845608*u) = 2^(x*(2.3022083 + 0.10294324*x^2)).
__device__ __forceinline__ unsigned int gelu2pk(f32x2 x) {
    f32x2 x2 = x * x;
    f32x2 t  = __builtin_elementwise_fma(x2, (f32x2)(0.10294324f),
                                         (f32x2)(2.3022083f));
    f32x2 a  = x * t;
    f32x2 e;
    e.x = __builtin_amdgcn_exp2f(a.x);
    e.y = __builtin_amdgcn_exp2f(a.y);
    f32x2 d = e + 1.0f;
    f32x2 r;
    r.x = __builtin_amdgcn_rcpf(d.x);
    r.y = __builtin_amdgcn_rcpf(d.y);
    f32x2 g = __builtin_elementwise_fma(-x, r, x);
    return pk2(g.x, g.y);
}

#define MFMA16(a, b, c) __builtin_amdgcn_mfma_f32_16x16x32_bf16(a, b, c, 0, 0, 0)

// DPP sum step within 16-lane row: 0x128=row_ror:8, 0x124=row_ror:4,
// 0x4E=quad_perm xor2, 0xB1=quad_perm xor1.
template<int CTRL>
__device__ __forceinline__ float dpp_add(float x) {
    int y = __builtin_amdgcn_update_dpp(0, __float_as_int(x), CTRL, 0xF, 0xF, true);
    return x + __int_as_float(y);
}
__device__ __forceinline__ float row16_sum(float x) {
    x = dpp_add<0x128>(x);
    x = dpp_add<0x124>(x);
    x = dpp_add<0x4E>(x);
    x = dpp_add<0xB1>(x);
    return x;
}

// ---- merged pre-pass: blocks 0..5 pack weights+biases; blocks >=6 cvt fy ----
// W1 (frags 0..7): B[k][n] identity-k with the agg permutation
//   (kp<32 -> fy row 6+kp; 32..37 -> y rows 0..5; 38 -> b1; else 0).
// W2 (frags 8..15), W3 (16..19): k-PERMUTED so layer-1/2 outputs feed the
//   next MFMA with no lane movement:
//   B[k=32kb+8q+j][n] = W[16*(m>>2) + 4q + (m&3)][n],  m = 8kb + j.
__global__ __launch_bounds__(256) void prep(
    const float* __restrict__ W1, const float* __restrict__ b1,
    const float* __restrict__ W2, const float* __restrict__ b2,
    const float* __restrict__ W3, const float* __restrict__ b3,
    unsigned short* __restrict__ wpack,
    const float* __restrict__ fy, unsigned short* __restrict__ fy16,
    int n8)
{
    if (blockIdx.x >= 6) {
        int i = (blockIdx.x - 6) * 256 + threadIdx.x;
        if (i >= n8) return;
        const float4* p = (const float4*)(fy + (size_t)i * 8);
        float4 a = p[0], b = p[1];
        *(uint4*)(fy16 + (size_t)i * 8) =
            make_uint4(pk2(a.x, a.y), pk2(a.z, a.w), pk2(b.x, b.y), pk2(b.z, b.w));
        return;
    }
    int t = blockIdx.x * 256 + threadIdx.x;
    if (t < 20 * 64) {
        int f = t >> 6, lane = t & 63;
        int quad = lane >> 4, c16 = lane & 15;
        unsigned short v8[8];
        if (f < 8) {
            int kb = f >> 2, nb = f & 3;
            #pragma unroll
            for (int j = 0; j < 8; ++j) {
                int kp = kb * 32 + quad * 8 + j;
                int n  = nb * 16 + c16;
                float v;
                if (kp < 32)      v = W1[(6 + kp) * 64 + n];
                else if (kp < 38) v = W1[(kp - 32) * 64 + n];
                else if (kp == 38) v = b1[n];
                else              v = 0.f;
                v8[j] = bf16rne(v);
            }
        } else if (f < 16) {
            int kb = (f - 8) >> 2, nb = (f - 8) & 3;
            #pragma unroll
            for (int j = 0; j < 8; ++j) {
                int m = 8 * kb + j;
                int row = 16 * (m >> 2) + 4 * quad + (m & 3);
                v8[j] = bf16rne(W2[row * 64 + nb * 16 + c16]);
            }
        } else {
            int kb = (f - 16) >> 1, nb = (f - 16) & 1;
            #pragma unroll
            for (int j = 0; j < 8; ++j) {
                int m = 8 * kb + j;
                int row = 16 * (m >> 2) + 4 * quad + (m & 3);
                v8[j] = bf16rne(W3[row * 32 + nb * 16 + c16]);
            }
        }
        uint4 o;
        o.x = (unsigned)v8[0] | ((unsigned)v8[1] << 16);
        o.y = (unsigned)v8[2] | ((unsigned)v8[3] << 16);
        o.z = (unsigned)v8[4] | ((unsigned)v8[5] << 16);
        o.w = (unsigned)v8[6] | ((unsigned)v8[7] << 16);
        *(uint4*)(wpack + (size_t)t * 8) = o;
    } else if (t < 1344) {               // b2tab: 64 floats
        int idx = t - 1280;
        float* btab = (float*)(wpack + 10240);
        btab[idx] = b2[16 * ((idx >> 2) & 3) + 4 * (idx >> 4) + (idx & 3)];
    } else if (t < 1376) {               // b3tab: 32 floats
        int idx = t - 1344;
        float* btab = (float*)(wpack + 10240);
        btab[64 + idx] = b3[16 * ((idx >> 2) & 1) + 4 * (idx >> 3) + (idx & 3)];
    }
}

__global__ __launch_bounds__(256, 4) void it_mfma(
    const float* __restrict__ y, const unsigned short* __restrict__ fy16,
    const float* __restrict__ wts,
    const unsigned short* __restrict__ wpack,
    const int* __restrict__ nbr,
    float* __restrict__ out, int npts)
{
    __shared__ unsigned short wlds[10432];   // 20864 B: frags + bias tables

    const int tid  = threadIdx.x;
    const int lane = tid & 63;
    const int wv   = tid >> 6;
    const int quad = lane >> 4;
    const int c16  = lane & 15;
    const int wgid   = blockIdx.x * 4 + wv;
    const int nwaves = gridDim.x * 4;

    // block-cooperative weight+bias load (before any early exit)
    {
        const uint4* src = (const uint4*)wpack;
        uint4* dst = (uint4*)wlds;
        #pragma unroll
        for (int i = 0; i < 6; ++i) {
            int idx = tid + i * 256;
            if (idx < 1304) dst[idx] = src[idx];
        }
    }
    __syncthreads();
    if (wgid >= npts) return;

    const floatx4 fz = {0.f, 0.f, 0.f, 0.f};
    const short8 s8z = {0,0,0,0,0,0,0,0};

    // ---- prologue: fetch first point's inputs (no shfl: direct loads) ----
    int p = wgid;
    int   j0c, j1c;
    short8 a0c[2];
    unsigned y0c[3] = {0u, 0u, 0u}, y1c[3] = {0u, 0u, 0u};
    {
        const int pu0 = __builtin_amdgcn_readfirstlane(p);
        j0c = nbr[pu0 * 32 + c16];
        j1c = nbr[pu0 * 32 + 16 + c16];
        a0c[0] = *(const short8*)(fy16 + (size_t)j0c * 32 + quad * 8);
        a0c[1] = *(const short8*)(fy16 + (size_t)j1c * 32 + quad * 8);
        if (quad == 0) {
            float xa = y[3*pu0], xb = y[3*pu0+1], xc = y[3*pu0+2];
            float ja = y[3*j0c], jb = y[3*j0c+1], jc = y[3*j0c+2];
            float ka = y[3*j1c], kb = y[3*j1c+1], kc = y[3*j1c+2];
            y0c[0] = pk2(ja, jb); y0c[1] = pk2(jc, xa); y0c[2] = pk2(xb, xc);
            y1c[0] = pk2(ka, kb); y1c[1] = pk2(kc, xa); y1c[2] = pk2(xb, xc);
        }
    }

    unsigned woff = 0;   // asm barrier keeps LDS frag reads loop-variant
                         // (anti-LICM: hoisting 20 frags into regs = v2 spill)

    for (;;) {
        asm volatile("" : "+v"(woff));
        const unsigned short* wp = wlds + woff;
        const float* bp = (const float*)((const char*)wp + 20480);
        #define WFRAG(fid) (*(const short8*)(wp + (((fid) * 64 + lane) * 8)))

        const int pu = __builtin_amdgcn_readfirstlane(p);
        const int pn = p + nwaves;
        const bool last = (pn >= npts);
        const int pncu = __builtin_amdgcn_readfirstlane(last ? p : pn);
        // issue next-point's nbr loads early (L1/L2-hot 64B broadcasts)
        int j0n = nbr[pncu * 32 + c16];
        int j1n = nbr[pncu * 32 + 16 + c16];

        // ---- assemble a1 operands (quad0; k=38 bias word = bf16(1.0)) ----
        short8 a1t0 = s8z, a1t1 = s8z;
        if (quad == 0) {
            union { short8 s; unsigned int u[4]; } c0, c1;
            c0.u[0] = y0c[0]; c0.u[1] = y0c[1]; c0.u[2] = y0c[2]; c0.u[3] = 0x00003f80u;
            c1.u[0] = y1c[0]; c1.u[1] = y1c[1]; c1.u[2] = y1c[2]; c1.u[3] = 0x00003f80u;
            a1t0 = c0.s; a1t1 = c1.s;
        }

        // ---- layer 1, both tiles (each W1 frag read once) ----
        floatx4 acc0[4], acc1[4];
        #pragma unroll
        for (int mb = 0; mb < 4; ++mb) {
            short8 w = WFRAG(mb);
            acc0[mb] = MFMA16(w, a0c[0], fz);
            acc1[mb] = MFMA16(w, a0c[1], fz);
        }
        #pragma unroll
        for (int mb = 0; mb < 4; ++mb) {
            short8 w = WFRAG(4 + mb);
            acc0[mb] = MFMA16(w, a1t0, acc0[mb]);
            acc1[mb] = MFMA16(w, a1t1, acc1[mb]);
        }

        // ---- gelu tile0 -> hb00/hb10 (VALU while matrix pipe drains L1) ----
        unsigned u0[8], u1[8];
        #pragma unroll
        for (int mb = 0; mb < 4; ++mb) {
            u0[mb*2]   = gelu2pk((f32x2){acc0[mb][0], acc0[mb][1]});
            u0[mb*2+1] = gelu2pk((f32x2){acc0[mb][2], acc0[mb][3]});
        }
        short8 hb00, hb10;
        {
            union { unsigned u[4]; short8 s; } c;
            c.u[0]=u0[0]; c.u[1]=u0[1]; c.u[2]=u0[2]; c.u[3]=u0[3]; hb00 = c.s;
            c.u[0]=u0[4]; c.u[1]=u0[5]; c.u[2]=u0[6]; c.u[3]=u0[7]; hb10 = c.s;
        }
        // ---- L2 tile0 into matrix pipe (acc0 L1 values already consumed) ----
        #pragma unroll
        for (int mb = 0; mb < 4; ++mb) {
            short8 w = WFRAG(8 + mb);
            acc0[mb] = MFMA16(w, hb00, fz);
        }
        #pragma unroll
        for (int mb = 0; mb < 4; ++mb) {
            short8 w = WFRAG(12 + mb);
            acc0[mb] = MFMA16(w, hb10, acc0[mb]);
        }

        // ---- prefetch next point (VALU/mem under L2-t0 MFMAs) ----
        short8 a0n[2];
        unsigned y0n[3] = {0u, 0u, 0u}, y1n[3] = {0u, 0u, 0u};
        {
            a0n[0] = *(const short8*)(fy16 + (size_t)j0n * 32 + quad * 8);
            a0n[1] = *(const short8*)(fy16 + (size_t)j1n * 32 + quad * 8);
            if (quad == 0) {
                float xa = y[3*pncu], xb = y[3*pncu+1], xc = y[3*pncu+2];
                float ja = y[3*j0n], jb = y[3*j0n+1], jc = y[3*j0n+2];
                float ka = y[3*j1n], kb = y[3*j1n+1], kc = y[3*j1n+2];
                y0n[0] = pk2(ja, jb); y0n[1] = pk2(jc, xa); y0n[2] = pk2(xb, xc);
                y1n[0] = pk2(ka, kb); y1n[1] = pk2(kc, xa); y1n[2] = pk2(xb, xc);
            }
        }

        // ---- gelu tile1 -> hb01/hb11 (under L2-t0) ----
        #pragma unroll
        for (int mb = 0; mb < 4; ++mb) {
            u1[mb*2]   = gelu2pk((f32x2){acc1[mb][0], acc1[mb][1]});
            u1[mb*2+1] = gelu2pk((f32x2){acc1[mb][2], acc1[mb][3]});
        }
        short8 hb01, hb11;
        {
            union { unsigned u[4]; short8 s; } c;
            c.u[0]=u1[0]; c.u[1]=u1[1]; c.u[2]=u1[2]; c.u[3]=u1[3]; hb01 = c.s;
            c.u[0]=u1[4]; c.u[1]=u1[5]; c.u[2]=u1[6]; c.u[3]=u1[7]; hb11 = c.s;
        }
        // ---- L2 tile1 ----
        #pragma unroll
        for (int mb = 0; mb < 4; ++mb) {
            short8 w = WFRAG(8 + mb);
            acc1[mb] = MFMA16(w, hb01, fz);
        }
        #pragma unroll
        for (int mb = 0; mb < 4; ++mb) {
            short8 w = WFRAG(12 + mb);
            acc1[mb] = MFMA16(w, hb11, acc1[mb]);
        }

        // ---- gelu2 tile0 -> gb00/gb10 (under L2-t1) ----
        #pragma unroll
        for (int mb = 0; mb < 4; ++mb) {
            floatx4 b2v = *(const floatx4*)(bp + quad * 16 + mb * 4);
            u0[mb*2]   = gelu2pk((f32x2){acc0[mb][0] + b2v[0], acc0[mb][1] + b2v[1]});
            u0[mb*2+1] = gelu2pk((f32x2){acc0[mb][2] + b2v[2], acc0[mb][3] + b2v[3]});
        }
        short8 gb00, gb10;
        {
            union { unsigned u[4]; short8 s; } c;
            c.u[0]=u0[0]; c.u[1]=u0[1]; c.u[2]=u0[2]; c.u[3]=u0[3]; gb00 = c.s;
            c.u[0]=u0[4]; c.u[1]=u0[5]; c.u[2]=u0[6]; c.u[3]=u0[7]; gb10 = c.s;
        }
        // ---- L3 tile0 ----
        floatx4 o00, o10;
        { short8 w = WFRAG(16); o00 = MFMA16(w, gb00, fz); }
        { short8 w = WFRAG(18); o00 = MFMA16(w, gb10, o00); }
        { short8 w = WFRAG(17); o10 = MFMA16(w, gb00, fz); }
        { short8 w = WFRAG(19); o10 = MFMA16(w, gb10, o10); }

        // ---- gelu2 tile1 -> gb01/gb11 (under L3-t0) ----
        #pragma unroll
        for (int mb = 0; mb < 4; ++mb) {
            floatx4 b2v = *(const floatx4*)(bp + quad * 16 + mb * 4);
            u1[mb*2]   = gelu2pk((f32x2){acc1[mb][0] + b2v[0], acc1[mb][1] + b2v[1]});
            u1[mb*2+1] = gelu2pk((f32x2){acc1[mb][2] + b2v[2], acc1[mb][3] + b2v[3]});
        }
        short8 gb01, gb11;
        {
            union { unsigned u[4]; short8 s; } c;
            c.u[0]=u1[0]; c.u[1]=u1[1]; c.u[2]=u1[2]; c.u[3]=u1[3]; gb01 = c.s;
            c.u[0]=u1[4]; c.u[1]=u1[5]; c.u[2]=u1[6]; c.u[3]=u1[7]; gb11 = c.s;
        }
        // ---- L3 tile1 (W3 frags re-read: +4 ds_read/point) ----
        floatx4 o01, o11;
        { short8 w = WFRAG(16); o01 = MFMA16(w, gb01, fz); }
        { short8 w = WFRAG(18); o01 = MFMA16(w, gb11, o01); }
        { short8 w = WFRAG(17); o11 = MFMA16(w, gb01, fz); }
        { short8 w = WFRAG(19); o11 = MFMA16(w, gb11, o11); }

        // wts loads (L1-hot broadcast); latency hides under L3 MFMAs
        float wac = wts[j0c], wbc = wts[j1c];

        floatx4 b3v0 = *(const floatx4*)(bp + 64 + quad * 8);
        floatx4 b3v1 = *(const floatx4*)(bp + 64 + quad * 8 + 4);

        // ---- epilogue: ch = 16mb + 4quad + r; edge c16 (t0) / 16+c16 (t1) ----
        float vs0[4] = {0.f, 0.f, 0.f, 0.f};
        float vs1[4] = {0.f, 0.f, 0.f, 0.f};
        {
            ushort4v fa = *(const ushort4v*)(fy16 + (size_t)j0c * 32 + 4 * quad);
            ushort4v fb = *(const ushort4v*)(fy16 + (size_t)j0c * 32 + 16 + 4 * quad);
            #pragma unroll
            for (int r = 0; r < 4; ++r) {
                vs0[r] = fmaf((o00[r] + b3v0[r]) * bf16f(fa[r]), wac, vs0[r]);
                vs1[r] = fmaf((o10[r] + b3v1[r]) * bf16f(fb[r]), wac, vs1[r]);
            }
        }
        {
            ushort4v fa = *(const ushort4v*)(fy16 + (size_t)j1c * 32 + 4 * quad);
            ushort4v fb = *(const ushort4v*)(fy16 + (size_t)j1c * 32 + 16 + 4 * quad);
            #pragma unroll
            for (int r = 0; r < 4; ++r) {
                vs0[r] = fmaf((o01[r] + b3v0[r]) * bf16f(fa[r]), wbc, vs0[r]);
                vs1[r] = fmaf((o11[r] + b3v1[r]) * bf16f(fb[r]), wbc, vs1[r]);
            }
        }
        #undef WFRAG

        // ---- reduce over the 16 edge-lanes via DPP (no DS ops) and store ----
        #pragma unroll
        for (int r = 0; r < 4; ++r) {
            vs0[r] = row16_sum(vs0[r]);
            vs1[r] = row16_sum(vs1[r]);
        }
        if (c16 == 0) {
            *(float4*)(out + (size_t)pu * 32 + 4 * quad) =
                make_float4(vs0[0], vs0[1], vs0[2], vs0[3]);
            *(float4*)(out + (size_t)pu * 32 + 16 + 4 * quad) =
                make_float4(vs1[0], vs1[1], vs1[2], vs1[3]);
        }

        if (last) break;
        p = pn;
        j0c = j0n; j1c = j1n;
        a0c[0] = a0n[0]; a0c[1] = a0n[1];
        y0c[0] = y0n[0]; y0c[1] = y0n[1]; y0c[2] = y0n[2];
        y1c[0] = y1n[0]; y1c[1] = y1n[1]; y1c[2] = y1n[2];
    }
}

extern "C" void kernel_launch(void* const* d_in, const int* in_sizes, int n_in,
                              void* d_out, int out_size, void* d_ws, size_t ws_size,
                              hipStream_t stream) {
    const float* y  = (const float*)d_in[0];
    const float* fy = (const float*)d_in[1];
    const float* wt = (const float*)d_in[2];
    const float* W1 = (const float*)d_in[3];
    const float* b1 = (const float*)d_in[4];
    const float* W2 = (const float*)d_in[5];
    const float* b2 = (const float*)d_in[6];
    const float* W3 = (const float*)d_in[7];
    const float* b3 = (const float*)d_in[8];
    const int* nbr  = (const int*)d_in[9];
    const int E = in_sizes[9];
    const int npts = E >> 5;              // K = 32 fixed
    float* out = (float*)d_out;

    // workspace: [0, 20864) packed frags + bias tables; [32768, ...) fy16
    unsigned short* wpack = (unsigned short*)d_ws;
    unsigned short* fy16  = (unsigned short*)((char*)d_ws + 32768);

    // single merged pre-pass (one launch)
    const int n8 = npts * 4;              // 8 floats per thread
    hipLaunchKernelGGL(prep, dim3(6 + (n8 + 255) / 256), dim3(256), 0, stream,
                       W1, b1, W2, b2, W3, b3, wpack, fy, fy16, n8);

    // grid 1792 (fills stragglers; beats exact-residency 1024). bounds
    // (256,4): uncapped allocator, spill-free 4 waves/SIMD (axis closed).
    hipLaunchKernelGGL(it_mfma, dim3(1792), dim3(256), 0, stream,
                       y, fy16, wt, wpack, nbr, out, npts);
}